// Round 21
// baseline (790.083 us; speedup 1.0000x reference)
//
#include <hip/hip_runtime.h>
#include <hip/hip_bf16.h>

// D=64, H=512, B=2048, S=16, C=256. Rows = 32768 independent samples, 64 AR steps.
#define ROWS 32      // rows per block
#define TPB 512      // 8 waves; 2 blocks/CU (16 waves/CU = register ceiling)

typedef unsigned short u16;
typedef __attribute__((ext_vector_type(8))) short bf16x8;
typedef __attribute__((ext_vector_type(16))) float f32x16;

__device__ __forceinline__ int deg_of_sorted(int i) {
  return (i < 72) ? (i / 9 + 1) : ((i - 8) / 8 + 1);
}
__device__ __forceinline__ int perm_of_sorted(int i) {
  int g, k;
  if (i < 72) { g = i / 9 + 1; k = i % 9; }
  else        { g = (i - 8) / 8 + 1; k = (i - 8) % 8; }
  return (g - 1) + 63 * k;
}
__device__ __forceinline__ int cum_deg(int d) {
  return (d <= 0) ? 0 : ((d <= 8) ? 9 * d : 8 * d + 8);
}
__device__ __forceinline__ u16 f2bfu(float x) {
  return __builtin_bit_cast(u16, __float2bfloat16(x));
}
__device__ __forceinline__ float softplus_f(float x) {
  return fmaxf(x, 0.f) + __logf(1.f + __expf(-fabsf(x)));
}

// ---------------- prep: permuted/masked weights ----------------
__global__ __launch_bounds__(256) void prep_w(
    const float* __restrict__ W1, const float* __restrict__ W2,
    const float* __restrict__ b2, const float* __restrict__ W3,
    float* __restrict__ mw1s, u16* __restrict__ mw2f,
    float* __restrict__ mw3f, float* __restrict__ b2s) {
  int idx = blockIdx.x * 256 + threadIdx.x;
  if (idx < 262144) {  // MW2 sorted+masked, MFMA fragment layout [(k>>3)][n][k&7]
    int kb = idx >> 12, n = (idx >> 3) & 511, kk = idx & 7;
    int k = kb * 8 + kk;
    float v = (deg_of_sorted(k) <= deg_of_sorted(n))
                  ? W2[perm_of_sorted(k) * 512 + perm_of_sorted(n)] : 0.f;
    mw2f[idx] = f2bfu(v);
    return;
  }
  idx -= 262144;
  if (idx < 32768) {   // MW1 sorted+masked rows d, cols sorted j (f32)
    int d = idx >> 9, j = idx & 511;
    mw1s[idx] = (deg_of_sorted(j) >= d + 1) ? W1[d * 512 + perm_of_sorted(j)] : 0.f;
    return;
  }
  idx -= 32768;
  if (idx < 65536) {   // MW3 transposed f32: [out col c(128)][sorted j(512)]
    int c = idx >> 9, j = idx & 511;
    mw3f[idx] = (deg_of_sorted(j) <= (c & 63)) ? W3[perm_of_sorted(j) * 128 + c] : 0.f;
    return;
  }
  idx -= 65536;
  if (idx < 512) b2s[idx] = b2[perm_of_sorted(idx)];
}

// ctx_proj with b-row reuse: 16 rows per block, Wc row read once per block per c
__global__ __launch_bounds__(512) void prep_ctx(
    const float* __restrict__ context, const float* __restrict__ Wc,
    const float* __restrict__ b1, float* __restrict__ ctxp) {
  __shared__ float cs[16][257];
  const int tid = threadIdx.x;
  const int b0  = blockIdx.x * 16;
  for (int i = tid; i < 16 * 256; i += 512) {
    int r = i >> 8, c = i & 255;
    cs[r][c] = context[(b0 + r) * 256 + c];
  }
  __syncthreads();
  const int j  = tid;
  const int pj = perm_of_sorted(j);
  float acc[16];
  const float bv = b1[pj];
  #pragma unroll
  for (int r = 0; r < 16; ++r) acc[r] = bv;
  for (int c = 0; c < 256; c += 4) {
    float w0 = Wc[(c + 0) * 512 + pj];
    float w1 = Wc[(c + 1) * 512 + pj];
    float w2 = Wc[(c + 2) * 512 + pj];
    float w3 = Wc[(c + 3) * 512 + pj];
    #pragma unroll
    for (int r = 0; r < 16; ++r) {
      acc[r] += cs[r][c + 0] * w0 + cs[r][c + 1] * w1 +
                cs[r][c + 2] * w2 + cs[r][c + 3] * w3;
    }
  }
  #pragma unroll
  for (int r = 0; r < 16; ++r) ctxp[(b0 + r) * 512 + j] = acc[r];
}

// ---- main: R17 structure + next-step B-fragment register prefetch ----
__global__ __launch_bounds__(TPB, 4) void made_main(
    const float* __restrict__ eps, const float* __restrict__ b3,
    const float* __restrict__ ctxp, const float* __restrict__ mw1s,
    const float* __restrict__ mw3f, const float* __restrict__ b2sg,
    const u16* __restrict__ mw2f, float* __restrict__ out) {
  __shared__ __align__(16) u16   dbuf[2][32][40];    //  5120 B delta h1, 80B row stride
  __shared__ __align__(16) float part2mu[16 * 33];   //  2112 B [wave*2+kq][row]
  __shared__ __align__(16) float part2sc[16 * 33];   //  2112 B
  __shared__ __align__(16) float w1s[512];           //  2048 B staged w1 row d
  __shared__ __align__(16) float w3fs[2][2][512];    //  8192 B staged w3 rows (dbuffered)
  __shared__ __align__(16) float b3s[128];           //   512 B
  __shared__ __align__(16) float epsall[ROWS * 65];  //  8320 B
  __shared__ __align__(16) float zLb[ROWS * 65];     //  8320 B
  __shared__ __align__(16) float muLb[ROWS * 65];    //  8320 B
  __shared__ __align__(16) float scLb[ROWS * 65];    //  8320 B
  // total ~53 KB -> 2 blocks/CU

  const int tid  = threadIdx.x;
  const int lane = tid & 63;
  const int wave = tid >> 6;               // 0..7
  const int g0   = blockIdx.x * ROWS;
  const int b0   = g0 & 2047;

  // a1 ownership: row rA = tid&31, cols [jA, jA+32)
  const int rA = tid & 31;
  const int jA = (tid >> 5) << 5;
  float a1r[32];
  #pragma unroll
  for (int t = 0; t < 8; ++t) {
    *(float4*)&a1r[t * 4] = *(const float4*)&ctxp[(b0 + rA) * 512 + jA + t * 4];
  }

  // init LDS: zero dbuf (1280 words), b3, eps, prologue w3fs[0]
  ((unsigned*)dbuf)[tid] = 0u;
  ((unsigned*)dbuf)[tid + 512] = 0u;
  if (tid < 256) ((unsigned*)dbuf)[tid + 1024] = 0u;
  if (tid < 128) b3s[tid] = b3[tid];
  {
    int r = tid >> 4, c = (tid & 15) * 4;
    float4 ev = *(const float4*)&eps[(g0 + r) * 64 + c];
    epsall[r * 65 + c + 0] = ev.x;
    epsall[r * 65 + c + 1] = ev.y;
    epsall[r * 65 + c + 2] = ev.z;
    epsall[r * 65 + c + 3] = ev.w;
  }
  if (tid < 256) {
    int c_sel = tid >> 7, j0 = (tid & 127) * 4;
    *(float4*)&w3fs[0][c_sel][j0] = *(const float4*)&mw3f[(c_sel * 64) * 512 + j0];
  }
  __syncthreads();

  const int m  = lane & 31;   // MFMA: A row (w2 col n) AND B col (h2 row r)
  const int kq = lane >> 5;   // k-half
  const int jt0 = wave;       // balanced pair per wave
  const int jt1 = 15 - wave;
  const u16* bLane = mw2f + ((kq * 512 + m) << 3);
  const u16* bp0   = bLane + jt0 * 256;
  const u16* bp1   = bLane + jt1 * 256;
  const int ke0full = cum_deg(deg_of_sorted(jt0 * 32 + 31));
  const int ke1full = cum_deg(deg_of_sorted(jt1 * 32 + 31));

  // persistent transposed layer-2 acc: lane = h2 ROW r(=m), regs = cols n_i (bias-init)
  f32x16 acc0, acc1;
  #pragma unroll
  for (int i = 0; i < 16; ++i) {
    const int ni = (i & 3) + 8 * (i >> 2) + 4 * kq;
    acc0[i] = b2sg[jt0 * 32 + ni];
    acc1[i] = b2sg[jt1 * 32 + ni];
  }

  // prefetched W2 fragments for the NEXT step's delta window (kb=0 for d=1)
  bf16x8 pfA0 = *(const bf16x8*)(bp0);
  bf16x8 pfA1 = *(const bf16x8*)(bp0 + 8192);
  bf16x8 pfB0 = *(const bf16x8*)(bp1);
  bf16x8 pfB1 = *(const bf16x8*)(bp1 + 8192);

  for (int d = 0; d < 64; ++d) {
    const int Cd    = cum_deg(d);
    const int Cnext = cum_deg(d + 1);
    const int Cprev = cum_deg(d - 1);       // d=0 -> 0
    const int cb    = d & 1;
    const int nb    = cb ^ 1;

    // --- stage-issue: w1 row d, w3 rows for step d+1 (R17 timing)
    float4 w1stg;
    if (tid < 128) w1stg = *(const float4*)&mw1s[d * 512 + tid * 4];
    float4 w3stg;
    int c_sel = 0, j0 = 0;
    if (tid >= 128 && tid < 384 && d < 63) {
      int t2 = tid - 128;
      c_sel = t2 >> 7; j0 = (t2 & 127) * 4;
      w3stg = *(const float4*)&mw3f[(c_sel * 64 + d + 1) * 512 + j0];
    }

    // --- Phase A: delta MFMA from prefetched fragments (window kb = Cprev>>4)
    if (d > 0) {
      const int kb  = Cprev >> 4;
      const int nks = ((Cd - 1) >> 4) - kb + 1;    // 1 or 2
      {
        bf16x8 dF = *(const bf16x8*)&dbuf[cb][m][kq * 8];
        if (ke0full > kb * 16)
          acc0 = __builtin_amdgcn_mfma_f32_32x32x16_bf16(pfA0, dF, acc0, 0, 0, 0);
        if (ke1full > kb * 16)
          acc1 = __builtin_amdgcn_mfma_f32_32x32x16_bf16(pfB0, dF, acc1, 0, 0, 0);
      }
      if (nks > 1) {
        bf16x8 dF = *(const bf16x8*)&dbuf[cb][m][16 + kq * 8];
        if (ke0full > (kb + 1) * 16)
          acc0 = __builtin_amdgcn_mfma_f32_32x32x16_bf16(pfA1, dF, acc0, 0, 0, 0);
        if (ke1full > (kb + 1) * 16)
          acc1 = __builtin_amdgcn_mfma_f32_32x32x16_bf16(pfB1, dF, acc1, 0, 0, 0);
      }
    }

    // --- prefetch W2 fragments for step d+1 (window base = Cd>>4); hides under B/B2/C
    {
      const int kbn  = (Cd >> 4) > 31 ? 31 : (Cd >> 4);
      const int kbn1 = kbn + 1 > 31 ? 31 : kbn + 1;
      pfA0 = *(const bf16x8*)(bp0 + kbn * 8192);
      pfA1 = *(const bf16x8*)(bp0 + kbn1 * 8192);
      pfB0 = *(const bf16x8*)(bp1 + kbn * 8192);
      pfB1 = *(const bf16x8*)(bp1 + kbn1 * 8192);
    }

    // --- Phase B: gated per-lane layer-3 dot (R17 form)
    {
      const float* w3c = &w3fs[cb][0][0];
      float pmu = 0.f, psc = 0.f;
      if (jt0 * 32 < Cd) {
        #pragma unroll
        for (int g = 0; g < 4; ++g) {
          const int n0 = jt0 * 32 + 8 * g + 4 * kq;
          const float4 m0 = *(const float4*)&w3c[n0];
          const float4 s0 = *(const float4*)&w3c[512 + n0];
          float h0 = fmaxf(acc0[4 * g + 0], 0.f);
          float h1 = fmaxf(acc0[4 * g + 1], 0.f);
          float h2 = fmaxf(acc0[4 * g + 2], 0.f);
          float h3 = fmaxf(acc0[4 * g + 3], 0.f);
          pmu += h0 * m0.x + h1 * m0.y + h2 * m0.z + h3 * m0.w;
          psc += h0 * s0.x + h1 * s0.y + h2 * s0.z + h3 * s0.w;
        }
      }
      if (jt1 * 32 < Cd) {
        #pragma unroll
        for (int g = 0; g < 4; ++g) {
          const int n1 = jt1 * 32 + 8 * g + 4 * kq;
          const float4 m1 = *(const float4*)&w3c[n1];
          const float4 s1 = *(const float4*)&w3c[512 + n1];
          float h0 = fmaxf(acc1[4 * g + 0], 0.f);
          float h1 = fmaxf(acc1[4 * g + 1], 0.f);
          float h2 = fmaxf(acc1[4 * g + 2], 0.f);
          float h3 = fmaxf(acc1[4 * g + 3], 0.f);
          pmu += h0 * m1.x + h1 * m1.y + h2 * m1.z + h3 * m1.w;
          psc += h0 * s1.x + h1 * s1.y + h2 * s1.z + h3 * s1.w;
        }
      }
      pmu += __shfl_xor(pmu, 32);
      psc += __shfl_xor(psc, 32);
      if (kq == 0) part2mu[wave * 33 + m] = pmu;
      else         part2sc[wave * 33 + m] = psc;
    }

    // zero next delta buffer (640 words; last read of it was >=1 barrier ago)
    ((unsigned*)dbuf[nb])[tid] = 0u;
    if (tid < 128) ((unsigned*)dbuf[nb])[512 + tid] = 0u;

    // stage-write (latency hidden under phase A/B)
    if (tid < 128) *(float4*)&w1s[tid * 4] = w1stg;
    else if (tid < 384 && d < 63) *(float4*)&w3fs[nb][c_sel][j0] = w3stg;
    __syncthreads();

    // --- B2 (replicated): sum 8 wave partials, softplus, sample
    float msum = b3s[d], ssum = b3s[64 + d];
    #pragma unroll
    for (int w = 0; w < 8; ++w) {
      msum += part2mu[w * 33 + rA];
      ssum += part2sc[w * 33 + rA];
    }
    const float mu = msum;
    const float sc = softplus_f(ssum);
    const float z  = fmaf(sc, epsall[rA * 65 + d], mu);
    if (tid < 32) {
      zLb[rA * 65 + d]  = z;
      muLb[rA * 65 + d] = mu;
      scLb[rA * 65 + d] = sc;
    }

    // --- Phase C: rank-1 a1 update (guard-free fast path) + freeze into next delta
    const int kbw = Cd >> 4;
    if (jA >= Cd) {                 // fully in suffix: no per-element guards
      #pragma unroll
      for (int i = 0; i < 32; ++i) a1r[i] += z * w1s[jA + i];
    } else if (jA + 31 >= Cd) {     // boundary wave only
      #pragma unroll
      for (int i = 0; i < 32; ++i) {
        int j = jA + i;
        if (j >= Cd) a1r[i] += z * w1s[j];
      }
    }
    if (jA < Cnext && jA + 31 >= Cd) {
      #pragma unroll
      for (int i = 0; i < 32; ++i) {
        int j = jA + i;
        if (j >= Cd && j < Cnext) {
          dbuf[nb][rA][j - kbw * 16] = f2bfu(fmaxf(a1r[i], 0.f));
        }
      }
    }
    __syncthreads();
  }

  // --- final coalesced flush of z/mu/sc
  {
    const int r = tid >> 4, c = (tid & 15) * 4;
    float4 zv, mv, sv;
    zv.x = zLb[r * 65 + c + 0]; zv.y = zLb[r * 65 + c + 1];
    zv.z = zLb[r * 65 + c + 2]; zv.w = zLb[r * 65 + c + 3];
    mv.x = muLb[r * 65 + c + 0]; mv.y = muLb[r * 65 + c + 1];
    mv.z = muLb[r * 65 + c + 2]; mv.w = muLb[r * 65 + c + 3];
    sv.x = scLb[r * 65 + c + 0]; sv.y = scLb[r * 65 + c + 1];
    sv.z = scLb[r * 65 + c + 2]; sv.w = scLb[r * 65 + c + 3];
    *(float4*)&out[(g0 + r) * 64 + c]           = zv;
    *(float4*)&out[2097152 + (g0 + r) * 64 + c] = mv;
    *(float4*)&out[4194304 + (g0 + r) * 64 + c] = sv;
  }
}

extern "C" void kernel_launch(void* const* d_in, const int* in_sizes, int n_in,
                              void* d_out, int out_size, void* d_ws, size_t ws_size,
                              hipStream_t stream) {
  (void)in_sizes; (void)n_in; (void)out_size; (void)ws_size;
  const float* context = (const float*)d_in[0];
  const float* eps     = (const float*)d_in[1];
  const float* W1      = (const float*)d_in[2];
  const float* Wc      = (const float*)d_in[3];
  const float* b1      = (const float*)d_in[4];
  const float* W2      = (const float*)d_in[5];
  const float* b2      = (const float*)d_in[6];
  const float* W3      = (const float*)d_in[7];
  const float* b3      = (const float*)d_in[8];
  float* out = (float*)d_out;

  // ws: ctxp f32[1048576] | mw1s f32[32768] | b2s f32[512] | mw3f f32[65536] | mw2f u16[262144]
  float* ws   = (float*)d_ws;
  float* ctxp = ws;
  float* mw1s = ctxp + 1048576;
  float* b2s  = mw1s + 32768;
  float* mw3f = b2s + 512;
  u16*   mw2f = (u16*)(mw3f + 65536);

  prep_w<<<1410, 256, 0, stream>>>(W1, W2, b2, W3, mw1s, mw2f, mw3f, b2s);
  prep_ctx<<<128, 512, 0, stream>>>(context, Wc, b1, ctxp);
  made_main<<<1024, TPB, 0, stream>>>(eps, b3, ctxp, mw1s, mw3f, b2s, mw2f, out);
}

// Round 22
// 662.127 us; speedup vs baseline: 1.1933x; 1.1933x over previous
//
#include <hip/hip_runtime.h>
#include <hip/hip_bf16.h>

// D=64, H=512, B=2048, S=16, C=256. Rows = 32768 independent samples, 64 AR steps.
#define ROWS 32      // rows per block
#define TPB 512      // 8 waves; 2 blocks/CU (16 waves/CU register ceiling)

typedef unsigned short u16;
typedef __attribute__((ext_vector_type(8))) short bf16x8;
typedef __attribute__((ext_vector_type(16))) float f32x16;

__device__ __forceinline__ int deg_of_sorted(int i) {
  return (i < 72) ? (i / 9 + 1) : ((i - 8) / 8 + 1);
}
__device__ __forceinline__ int perm_of_sorted(int i) {
  int g, k;
  if (i < 72) { g = i / 9 + 1; k = i % 9; }
  else        { g = (i - 8) / 8 + 1; k = (i - 8) % 8; }
  return (g - 1) + 63 * k;
}
__device__ __forceinline__ int cum_deg(int d) {
  return (d <= 0) ? 0 : ((d <= 8) ? 9 * d : 8 * d + 8);
}
__device__ __forceinline__ u16 f2bfu(float x) {
  return __builtin_bit_cast(u16, __float2bfloat16(x));
}
__device__ __forceinline__ float softplus_f(float x) {
  return fmaxf(x, 0.f) + __logf(1.f + __expf(-fabsf(x)));
}

// ---------------- prep kernels (unchanged, proven) ----------------
__global__ __launch_bounds__(256) void prep_w(
    const float* __restrict__ W1, const float* __restrict__ W2,
    const float* __restrict__ b2, const float* __restrict__ W3,
    float* __restrict__ mw1s, u16* __restrict__ mw2f,
    float* __restrict__ mw3f, float* __restrict__ b2s) {
  int idx = blockIdx.x * 256 + threadIdx.x;
  if (idx < 262144) {  // MW2 sorted+masked, MFMA fragment layout [(k>>3)][n][k&7]
    int kb = idx >> 12, n = (idx >> 3) & 511, kk = idx & 7;
    int k = kb * 8 + kk;
    float v = (deg_of_sorted(k) <= deg_of_sorted(n))
                  ? W2[perm_of_sorted(k) * 512 + perm_of_sorted(n)] : 0.f;
    mw2f[idx] = f2bfu(v);
    return;
  }
  idx -= 262144;
  if (idx < 32768) {   // MW1 sorted+masked rows d, cols sorted j (f32)
    int d = idx >> 9, j = idx & 511;
    mw1s[idx] = (deg_of_sorted(j) >= d + 1) ? W1[d * 512 + perm_of_sorted(j)] : 0.f;
    return;
  }
  idx -= 32768;
  if (idx < 65536) {   // MW3 transposed f32: [out col c(128)][sorted j(512)]
    int c = idx >> 9, j = idx & 511;
    mw3f[idx] = (deg_of_sorted(j) <= (c & 63)) ? W3[perm_of_sorted(j) * 128 + c] : 0.f;
    return;
  }
  idx -= 65536;
  if (idx < 512) b2s[idx] = b2[perm_of_sorted(idx)];
}

__global__ __launch_bounds__(512) void prep_ctx(
    const float* __restrict__ context, const float* __restrict__ Wc,
    const float* __restrict__ b1, float* __restrict__ ctxp) {
  __shared__ float cs[16][257];
  const int tid = threadIdx.x;
  const int b0  = blockIdx.x * 16;
  for (int i = tid; i < 16 * 256; i += 512) {
    int r = i >> 8, c = i & 255;
    cs[r][c] = context[(b0 + r) * 256 + c];
  }
  __syncthreads();
  const int j  = tid;
  const int pj = perm_of_sorted(j);
  float acc[16];
  const float bv = b1[pj];
  #pragma unroll
  for (int r = 0; r < 16; ++r) acc[r] = bv;
  for (int c = 0; c < 256; c += 4) {
    float w0 = Wc[(c + 0) * 512 + pj];
    float w1 = Wc[(c + 1) * 512 + pj];
    float w2 = Wc[(c + 2) * 512 + pj];
    float w3 = Wc[(c + 3) * 512 + pj];
    #pragma unroll
    for (int r = 0; r < 16; ++r) {
      acc[r] += cs[r][c + 0] * w0 + cs[r][c + 1] * w1 +
                cs[r][c + 2] * w2 + cs[r][c + 3] * w3;
    }
  }
  #pragma unroll
  for (int r = 0; r < 16; ++r) ctxp[(b0 + r) * 512 + j] = acc[r];
}

// ---- main: ONE barrier/step; seeds + lane-local frag build (no dbuf round trip) ----
__global__ __launch_bounds__(TPB, 4) void made_main(
    const float* __restrict__ eps, const float* __restrict__ b3,
    const float* __restrict__ ctxp, const float* __restrict__ mw1s,
    const float* __restrict__ mw3f, const float* __restrict__ b2sg,
    const u16* __restrict__ mw2f, float* __restrict__ out) {
  __shared__ __align__(16) float seedbuf[2][32][34];  //  8704 B raw a1 seeds (pad: 2-way)
  __shared__ __align__(16) float part2mu[8 * 33];     //  1056 B
  __shared__ __align__(16) float part2sc[8 * 33];     //  1056 B
  __shared__ __align__(16) float w1fs[2][512];        //  4096 B w1 rows (dbuffered)
  __shared__ __align__(16) float w3fs[2][2][512];     //  8192 B w3 rows (dbuffered)
  __shared__ __align__(16) float b3s[128];            //   512 B
  __shared__ __align__(16) float epsall[ROWS * 65];   //  8320 B
  __shared__ __align__(16) float zLb[ROWS * 65];      //  8320 B
  __shared__ __align__(16) float muLb[ROWS * 65];     //  8320 B
  __shared__ __align__(16) float scLb[ROWS * 65];     //  8320 B
  // total ~57 KB -> 2 blocks/CU

  const int tid  = threadIdx.x;
  const int lane = tid & 63;
  const int wave = tid >> 6;               // 0..7
  const int g0   = blockIdx.x * ROWS;
  const int b0   = g0 & 2047;

  // a1 ownership: row rA = tid&31, cols [jA, jA+32)
  const int rA = tid & 31;
  const int jA = (tid >> 5) << 5;
  float a1r[32];
  #pragma unroll
  for (int t = 0; t < 8; ++t) {
    *(float4*)&a1r[t * 4] = *(const float4*)&ctxp[(b0 + rA) * 512 + jA + t * 4];
  }

  // prologue: zero part2; b3; eps; w1fs[0]=row0; w3fs[0]=rows(1,65); seeds W_0 (raw ctx)
  if (tid < 264) { part2mu[tid] = 0.f; part2sc[tid] = 0.f; }
  if (tid < 128) {
    b3s[tid] = b3[tid];
    *(float4*)&w1fs[0][tid * 4] = *(const float4*)&mw1s[tid * 4];
  }
  {
    int r = tid >> 4, c = (tid & 15) * 4;
    float4 ev = *(const float4*)&eps[(g0 + r) * 64 + c];
    epsall[r * 65 + c + 0] = ev.x;
    epsall[r * 65 + c + 1] = ev.y;
    epsall[r * 65 + c + 2] = ev.z;
    epsall[r * 65 + c + 3] = ev.w;
  }
  if (tid >= 128 && tid < 384) {
    int t2 = tid - 128, c_sel = t2 >> 7, j0 = (t2 & 127) * 4;
    *(float4*)&w3fs[0][c_sel][j0] = *(const float4*)&mw3f[(c_sel * 64 + 1) * 512 + j0];
  }
  if (tid < 32) {   // W_0 = [0, 9): raw ctx seeds into buffer 1 (read at d=0)
    #pragma unroll
    for (int j = 0; j < 9; ++j) seedbuf[1][tid][j] = a1r[j];
  }

  const int m  = lane & 31;   // h2 row (MFMA D col); also B2/output row
  const int kq = lane >> 5;
  const int jt0 = wave;       // balanced tile pair
  const int jt1 = 15 - wave;
  const u16* bLane = mw2f + ((kq * 512 + m) << 3);
  const u16* bp0   = bLane + jt0 * 256;
  const u16* bp1   = bLane + jt1 * 256;
  const int ke0full = cum_deg(deg_of_sorted(jt0 * 32 + 31));
  const int ke1full = cum_deg(deg_of_sorted(jt1 * 32 + 31));

  // persistent transposed layer-2 acc (bias-init); lane = h2 row m, regs = cols n_i
  f32x16 acc0, acc1;
  #pragma unroll
  for (int i = 0; i < 16; ++i) {
    const int ni = (i & 3) + 8 * (i >> 2) + 4 * kq;
    acc0[i] = b2sg[jt0 * 32 + ni];
    acc1[i] = b2sg[jt1 * 32 + ni];
  }

  for (int d = 0; d < 64; ++d) {
    __syncthreads();   // the ONE barrier per step
    const int Cd    = cum_deg(d);
    const int Cnext = (d >= 63) ? 512 : cum_deg(d + 1);
    const int Cnn   = (d >= 62) ? 512 : cum_deg(d + 2);
    const int cb    = d & 1;
    const int nb    = cb ^ 1;

    // stage-issue for step d+1 (w1 row d+1; w3 rows for out-col d+2)
    float4 w1stg, w3stg;
    int c_sel = 0, j0 = 0;
    if (d < 63) {
      if (tid < 128) w1stg = *(const float4*)&mw1s[(d + 1) * 512 + tid * 4];
      else if (tid < 384) {
        int t2 = tid - 128;
        c_sel = t2 >> 7; j0 = (t2 & 127) * 4;
        int dc = (d + 2 > 63) ? 63 : d + 2;
        w3stg = *(const float4*)&mw3f[(c_sel * 64 + dc) * 512 + j0];
      }
    }

    // (a) B2: z_d from part2 written at step d-1 (zeros at d=0)
    float z;
    {
      const float* pb = kq ? &part2sc[0] : &part2mu[0];
      float own = kq ? b3s[64 + d] : b3s[d];
      #pragma unroll
      for (int s = 0; s < 8; ++s) own += pb[s * 33 + m];
      float other = __shfl_xor(own, 32);
      float mu = kq ? other : own;
      float sc = softplus_f(kq ? own : other);
      z = fmaf(sc, epsall[m * 65 + d], mu);
      if (tid < 32) {
        zLb[m * 65 + d]  = z;
        muLb[m * 65 + d] = mu;
        scLb[m * 65 + d] = sc;
      }
    }

    // (c) build W_d fragment lane-locally (seed + z_d*w1[d], relu) and (d') MFMA
    {
      const int base = Cd & ~15;
      const int lo = Cd - base, hi = Cnext - base;   // hi<=24; empty at d=63
      if (hi > lo) {
        bf16x8 f0 = {}, f1 = {};
        const float* sb  = &seedbuf[nb][m][0];       // written at step d-1
        const float* w1c = &w1fs[cb][0];
        #pragma unroll
        for (int e = 0; e < 8; ++e) {
          const int k0 = kq * 8 + e;
          const int k1 = 16 + kq * 8 + e;
          if (k0 >= lo && k0 < hi)
            f0[e] = (short)f2bfu(fmaxf(sb[k0] + z * w1c[base + k0], 0.f));
          if (k1 >= lo && k1 < hi)
            f1[e] = (short)f2bfu(fmaxf(sb[k1] + z * w1c[base + k1], 0.f));
        }
        const int ks0 = base >> 4;
        if (ke0full > ks0 * 16) {
          bf16x8 wA = *(const bf16x8*)(bp0 + ks0 * 8192);
          acc0 = __builtin_amdgcn_mfma_f32_32x32x16_bf16(wA, f0, acc0, 0, 0, 0);
        }
        if (ke1full > ks0 * 16) {
          bf16x8 wB = *(const bf16x8*)(bp1 + ks0 * 8192);
          acc1 = __builtin_amdgcn_mfma_f32_32x32x16_bf16(wB, f0, acc1, 0, 0, 0);
        }
        if (hi > 16) {
          if (ke0full > (ks0 + 1) * 16) {
            bf16x8 wA = *(const bf16x8*)(bp0 + (ks0 + 1) * 8192);
            acc0 = __builtin_amdgcn_mfma_f32_32x32x16_bf16(wA, f1, acc0, 0, 0, 0);
          }
          if (ke1full > (ks0 + 1) * 16) {
            bf16x8 wB = *(const bf16x8*)(bp1 + (ks0 + 1) * 8192);
            acc1 = __builtin_amdgcn_mfma_f32_32x32x16_bf16(wB, f1, acc1, 0, 0, 0);
          }
        }
      }
    }

    // (b) owner a1 update (j >= Cnext; frozen window cols handled by builders)
    if (jA >= Cnext) {
      #pragma unroll
      for (int i = 0; i < 32; ++i) a1r[i] += z * w1fs[cb][jA + i];
    } else if (jA + 31 >= Cnext) {
      #pragma unroll
      for (int i = 0; i < 32; ++i) {
        int j = jA + i;
        if (j >= Cnext) a1r[i] += z * w1fs[cb][j];
      }
    }
    // seed-write for W_{d+1} = [Cnext, Cnn) into seedbuf[cb] (read at step d+1)
    if (Cnn > Cnext && jA < Cnn && jA + 31 >= Cnext) {
      const int sbase = Cnext & ~15;
      #pragma unroll
      for (int i = 0; i < 32; ++i) {
        int j = jA + i;
        if (j >= Cnext && j < Cnn) seedbuf[cb][rA][j - sbase] = a1r[i];
      }
    }

    // (e) dot gated C_{d+1} -> part2 (feeds z_{d+1}); (f) stage-write. Skip at d=63.
    if (d < 63) {
      const float* w3c = &w3fs[cb][0][0];
      float pmu = 0.f, psc = 0.f;
      if (jt0 * 32 < Cnext) {
        #pragma unroll
        for (int g = 0; g < 4; ++g) {
          const int n0 = jt0 * 32 + 8 * g + 4 * kq;
          const float4 m0 = *(const float4*)&w3c[n0];
          const float4 s0 = *(const float4*)&w3c[512 + n0];
          float h0 = fmaxf(acc0[4 * g + 0], 0.f);
          float h1 = fmaxf(acc0[4 * g + 1], 0.f);
          float h2 = fmaxf(acc0[4 * g + 2], 0.f);
          float h3 = fmaxf(acc0[4 * g + 3], 0.f);
          pmu += h0 * m0.x + h1 * m0.y + h2 * m0.z + h3 * m0.w;
          psc += h0 * s0.x + h1 * s0.y + h2 * s0.z + h3 * s0.w;
        }
      }
      if (jt1 * 32 < Cnext) {
        #pragma unroll
        for (int g = 0; g < 4; ++g) {
          const int n1 = jt1 * 32 + 8 * g + 4 * kq;
          const float4 m1 = *(const float4*)&w3c[n1];
          const float4 s1 = *(const float4*)&w3c[512 + n1];
          float h0 = fmaxf(acc1[4 * g + 0], 0.f);
          float h1 = fmaxf(acc1[4 * g + 1], 0.f);
          float h2 = fmaxf(acc1[4 * g + 2], 0.f);
          float h3 = fmaxf(acc1[4 * g + 3], 0.f);
          pmu += h0 * m1.x + h1 * m1.y + h2 * m1.z + h3 * m1.w;
          psc += h0 * s1.x + h1 * s1.y + h2 * s1.z + h3 * s1.w;
        }
      }
      pmu += __shfl_xor(pmu, 32);
      psc += __shfl_xor(psc, 32);
      if (kq == 0) part2mu[wave * 33 + m] = pmu;
      else         part2sc[wave * 33 + m] = psc;

      if (tid < 128) *(float4*)&w1fs[nb][tid * 4] = w1stg;
      else if (tid < 384) *(float4*)&w3fs[nb][c_sel][j0] = w3stg;
    }
  }
  __syncthreads();

  // final coalesced flush of z/mu/sc
  {
    const int r = tid >> 4, c = (tid & 15) * 4;
    float4 zv, mv, sv;
    zv.x = zLb[r * 65 + c + 0]; zv.y = zLb[r * 65 + c + 1];
    zv.z = zLb[r * 65 + c + 2]; zv.w = zLb[r * 65 + c + 3];
    mv.x = muLb[r * 65 + c + 0]; mv.y = muLb[r * 65 + c + 1];
    mv.z = muLb[r * 65 + c + 2]; mv.w = muLb[r * 65 + c + 3];
    sv.x = scLb[r * 65 + c + 0]; sv.y = scLb[r * 65 + c + 1];
    sv.z = scLb[r * 65 + c + 2]; sv.w = scLb[r * 65 + c + 3];
    *(float4*)&out[(g0 + r) * 64 + c]           = zv;
    *(float4*)&out[2097152 + (g0 + r) * 64 + c] = mv;
    *(float4*)&out[4194304 + (g0 + r) * 64 + c] = sv;
  }
}

extern "C" void kernel_launch(void* const* d_in, const int* in_sizes, int n_in,
                              void* d_out, int out_size, void* d_ws, size_t ws_size,
                              hipStream_t stream) {
  (void)in_sizes; (void)n_in; (void)out_size; (void)ws_size;
  const float* context = (const float*)d_in[0];
  const float* eps     = (const float*)d_in[1];
  const float* W1      = (const float*)d_in[2];
  const float* Wc      = (const float*)d_in[3];
  const float* b1      = (const float*)d_in[4];
  const float* W2      = (const float*)d_in[5];
  const float* b2      = (const float*)d_in[6];
  const float* W3      = (const float*)d_in[7];
  const float* b3      = (const float*)d_in[8];
  float* out = (float*)d_out;

  // ws: ctxp f32[1048576] | mw1s f32[32768] | b2s f32[512] | mw3f f32[65536] | mw2f u16[262144]
  float* ws   = (float*)d_ws;
  float* ctxp = ws;
  float* mw1s = ctxp + 1048576;
  float* b2s  = mw1s + 32768;
  float* mw3f = b2s + 512;
  u16*   mw2f = (u16*)(mw3f + 65536);

  prep_w<<<1410, 256, 0, stream>>>(W1, W2, b2, W3, mw1s, mw2f, mw3f, b2s);
  prep_ctx<<<128, 512, 0, stream>>>(context, Wc, b1, ctxp);
  made_main<<<1024, TPB, 0, stream>>>(eps, b3, ctxp, mw1s, mw3f, b2s, mw2f, out);
}

// Round 23
// 619.996 us; speedup vs baseline: 1.2743x; 1.0680x over previous
//
#include <hip/hip_runtime.h>
#include <hip/hip_bf16.h>

// D=64, H=512, B=2048, S=16, C=256. Rows = 32768 independent samples, 64 AR steps.
#define ROWS 32      // rows per block
#define TPB 512      // 8 waves; 2 blocks/CU (16 waves/CU = register ceiling)

typedef unsigned short u16;
typedef __attribute__((ext_vector_type(8))) short bf16x8;
typedef __attribute__((ext_vector_type(16))) float f32x16;

__device__ __forceinline__ int deg_of_sorted(int i) {
  return (i < 72) ? (i / 9 + 1) : ((i - 8) / 8 + 1);
}
__device__ __forceinline__ int perm_of_sorted(int i) {
  int g, k;
  if (i < 72) { g = i / 9 + 1; k = i % 9; }
  else        { g = (i - 8) / 8 + 1; k = (i - 8) % 8; }
  return (g - 1) + 63 * k;
}
__device__ __forceinline__ int cum_deg(int d) {
  return (d <= 0) ? 0 : ((d <= 8) ? 9 * d : 8 * d + 8);
}
__device__ __forceinline__ u16 f2bfu(float x) {
  return __builtin_bit_cast(u16, __float2bfloat16(x));
}
__device__ __forceinline__ float softplus_f(float x) {
  // fast: v_exp/v_log hardware ops; |err| ~1e-7 << 1.5e-2 budget
  return fmaxf(x, 0.f) + __logf(1.f + __expf(-fabsf(x)));
}

// ---------------- prep: permuted/masked weights ----------------
__global__ __launch_bounds__(256) void prep_w(
    const float* __restrict__ W1, const float* __restrict__ W2,
    const float* __restrict__ b2, const float* __restrict__ W3,
    float* __restrict__ mw1s, u16* __restrict__ mw2f,
    float* __restrict__ mw3f, float* __restrict__ b2s) {
  int idx = blockIdx.x * 256 + threadIdx.x;
  if (idx < 262144) {  // MW2 sorted+masked, MFMA fragment layout [(k>>3)][n][k&7]
    int kb = idx >> 12, n = (idx >> 3) & 511, kk = idx & 7;
    int k = kb * 8 + kk;
    float v = (deg_of_sorted(k) <= deg_of_sorted(n))
                  ? W2[perm_of_sorted(k) * 512 + perm_of_sorted(n)] : 0.f;
    mw2f[idx] = f2bfu(v);
    return;
  }
  idx -= 262144;
  if (idx < 32768) {   // MW1 sorted+masked rows d, cols sorted j (f32)
    int d = idx >> 9, j = idx & 511;
    mw1s[idx] = (deg_of_sorted(j) >= d + 1) ? W1[d * 512 + perm_of_sorted(j)] : 0.f;
    return;
  }
  idx -= 32768;
  if (idx < 65536) {   // MW3 transposed f32: [out col c(128)][sorted j(512)]
    int c = idx >> 9, j = idx & 511;
    mw3f[idx] = (deg_of_sorted(j) <= (c & 63)) ? W3[perm_of_sorted(j) * 128 + c] : 0.f;
    return;
  }
  idx -= 65536;
  if (idx < 512) b2s[idx] = b2[perm_of_sorted(idx)];
}

// ctx_proj with b-row reuse: 16 rows per block, Wc row read once per block per c
__global__ __launch_bounds__(512) void prep_ctx(
    const float* __restrict__ context, const float* __restrict__ Wc,
    const float* __restrict__ b1, float* __restrict__ ctxp) {
  __shared__ float cs[16][257];
  const int tid = threadIdx.x;
  const int b0  = blockIdx.x * 16;
  for (int i = tid; i < 16 * 256; i += 512) {
    int r = i >> 8, c = i & 255;
    cs[r][c] = context[(b0 + r) * 256 + c];
  }
  __syncthreads();
  const int j  = tid;
  const int pj = perm_of_sorted(j);
  float acc[16];
  const float bv = b1[pj];
  #pragma unroll
  for (int r = 0; r < 16; ++r) acc[r] = bv;
  for (int c = 0; c < 256; c += 4) {
    float w0 = Wc[(c + 0) * 512 + pj];
    float w1 = Wc[(c + 1) * 512 + pj];
    float w2 = Wc[(c + 2) * 512 + pj];
    float w3 = Wc[(c + 3) * 512 + pj];
    #pragma unroll
    for (int r = 0; r < 16; ++r) {
      acc[r] += cs[r][c + 0] * w0 + cs[r][c + 1] * w1 +
                cs[r][c + 2] * w2 + cs[r][c + 3] * w3;
    }
  }
  #pragma unroll
  for (int r = 0; r < 16; ++r) ctxp[(b0 + r) * 512 + j] = acc[r];
}

// ---- main: persistent TRANSPOSED layer-2 acc; padded dbuf; lean phase C ----
__global__ __launch_bounds__(TPB, 4) void made_main(
    const float* __restrict__ eps, const float* __restrict__ b3,
    const float* __restrict__ ctxp, const float* __restrict__ mw1s,
    const float* __restrict__ mw3f, const float* __restrict__ b2sg,
    const u16* __restrict__ mw2f, float* __restrict__ out) {
  __shared__ __align__(16) u16   dbuf[2][32][40];    //  5120 B delta h1, 80B row stride
  __shared__ __align__(16) float part2mu[16 * 33];   //  2112 B [wave*2+kq][row]
  __shared__ __align__(16) float part2sc[16 * 33];   //  2112 B
  __shared__ __align__(16) float w1s[512];           //  2048 B staged w1 row d
  __shared__ __align__(16) float w3fs[2][2][512];    //  8192 B staged w3 rows (dbuffered)
  __shared__ __align__(16) float b3s[128];           //   512 B
  __shared__ __align__(16) float epsall[ROWS * 65];  //  8320 B
  __shared__ __align__(16) float zLb[ROWS * 65];     //  8320 B
  __shared__ __align__(16) float muLb[ROWS * 65];    //  8320 B
  __shared__ __align__(16) float scLb[ROWS * 65];    //  8320 B
  // total ~53 KB -> 2 blocks/CU

  const int tid  = threadIdx.x;
  const int lane = tid & 63;
  const int wave = tid >> 6;               // 0..7
  const int g0   = blockIdx.x * ROWS;
  const int b0   = g0 & 2047;

  // a1 ownership: row rA = tid&31, cols [jA, jA+32)
  const int rA = tid & 31;
  const int jA = (tid >> 5) << 5;
  float a1r[32];
  #pragma unroll
  for (int t = 0; t < 8; ++t) {
    *(float4*)&a1r[t * 4] = *(const float4*)&ctxp[(b0 + rA) * 512 + jA + t * 4];
  }

  // init LDS: zero dbuf (1280 words), b3, eps, prologue w3fs[0]
  ((unsigned*)dbuf)[tid] = 0u;
  ((unsigned*)dbuf)[tid + 512] = 0u;
  if (tid < 256) ((unsigned*)dbuf)[tid + 1024] = 0u;
  if (tid < 128) b3s[tid] = b3[tid];
  {
    int r = tid >> 4, c = (tid & 15) * 4;
    float4 ev = *(const float4*)&eps[(g0 + r) * 64 + c];
    epsall[r * 65 + c + 0] = ev.x;
    epsall[r * 65 + c + 1] = ev.y;
    epsall[r * 65 + c + 2] = ev.z;
    epsall[r * 65 + c + 3] = ev.w;
  }
  if (tid < 256) {
    int c_sel = tid >> 7, j0 = (tid & 127) * 4;
    *(float4*)&w3fs[0][c_sel][j0] = *(const float4*)&mw3f[(c_sel * 64) * 512 + j0];
  }
  __syncthreads();

  const int m  = lane & 31;   // MFMA: A row (w2 col n) AND B col (h2 row r)
  const int kq = lane >> 5;   // k-half
  const int jt0 = wave;       // balanced pair per wave
  const int jt1 = 15 - wave;
  const u16* bLane = mw2f + ((kq * 512 + m) << 3);
  const u16* bp0   = bLane + jt0 * 256;
  const u16* bp1   = bLane + jt1 * 256;
  const int ke0full = cum_deg(deg_of_sorted(jt0 * 32 + 31));
  const int ke1full = cum_deg(deg_of_sorted(jt1 * 32 + 31));

  // persistent transposed layer-2 acc: lane = h2 ROW r(=m), regs = cols n_i (bias-init)
  f32x16 acc0, acc1;
  #pragma unroll
  for (int i = 0; i < 16; ++i) {
    const int ni = (i & 3) + 8 * (i >> 2) + 4 * kq;
    acc0[i] = b2sg[jt0 * 32 + ni];
    acc1[i] = b2sg[jt1 * 32 + ni];
  }

  for (int d = 0; d < 64; ++d) {
    const int Cd    = cum_deg(d);
    const int Cnext = cum_deg(d + 1);
    const int Cprev = cum_deg(d - 1);       // d=0 -> 0
    const int cb    = d & 1;
    const int nb    = cb ^ 1;

    // --- stage-issue: w1 row d, w3 rows for step d+1
    float4 w1stg;
    if (tid < 128) w1stg = *(const float4*)&mw1s[d * 512 + tid * 4];
    float4 w3stg;
    int c_sel = 0, j0 = 0;
    if (tid >= 128 && tid < 384 && d < 63) {
      int t2 = tid - 128;
      c_sel = t2 >> 7; j0 = (t2 & 127) * 4;
      w3stg = *(const float4*)&mw3f[(c_sel * 64 + d + 1) * 512 + j0];
    }

    // --- Phase A: delta MFMA (swapped operands -> transposed acc)
    if (d > 0) {
      const int kb  = Cprev >> 4;
      const int nks = ((Cd - 1) >> 4) - kb + 1;    // 1 or 2
      #pragma unroll 2
      for (int t = 0; t < nks; ++t) {
        const int ks = kb + t;
        bf16x8 dF = *(const bf16x8*)&dbuf[cb][m][t * 16 + kq * 8];
        if (ke0full > ks * 16) {
          bf16x8 wA = *(const bf16x8*)(bp0 + ks * 8192);
          acc0 = __builtin_amdgcn_mfma_f32_32x32x16_bf16(wA, dF, acc0, 0, 0, 0);
        }
        if (ke1full > ks * 16) {
          bf16x8 wB = *(const bf16x8*)(bp1 + ks * 8192);
          acc1 = __builtin_amdgcn_mfma_f32_32x32x16_bf16(wB, dF, acc1, 0, 0, 0);
        }
      }
    }

    // --- Phase B: gated per-lane layer-3 dot (wave-uniform gates, no divergence)
    {
      const float* w3c = &w3fs[cb][0][0];
      float pmu = 0.f, psc = 0.f;
      if (jt0 * 32 < Cd) {
        #pragma unroll
        for (int g = 0; g < 4; ++g) {
          const int n0 = jt0 * 32 + 8 * g + 4 * kq;
          const float4 m0 = *(const float4*)&w3c[n0];
          const float4 s0 = *(const float4*)&w3c[512 + n0];
          float h0 = fmaxf(acc0[4 * g + 0], 0.f);
          float h1 = fmaxf(acc0[4 * g + 1], 0.f);
          float h2 = fmaxf(acc0[4 * g + 2], 0.f);
          float h3 = fmaxf(acc0[4 * g + 3], 0.f);
          pmu += h0 * m0.x + h1 * m0.y + h2 * m0.z + h3 * m0.w;
          psc += h0 * s0.x + h1 * s0.y + h2 * s0.z + h3 * s0.w;
        }
      }
      if (jt1 * 32 < Cd) {
        #pragma unroll
        for (int g = 0; g < 4; ++g) {
          const int n1 = jt1 * 32 + 8 * g + 4 * kq;
          const float4 m1 = *(const float4*)&w3c[n1];
          const float4 s1 = *(const float4*)&w3c[512 + n1];
          float h0 = fmaxf(acc1[4 * g + 0], 0.f);
          float h1 = fmaxf(acc1[4 * g + 1], 0.f);
          float h2 = fmaxf(acc1[4 * g + 2], 0.f);
          float h3 = fmaxf(acc1[4 * g + 3], 0.f);
          pmu += h0 * m1.x + h1 * m1.y + h2 * m1.z + h3 * m1.w;
          psc += h0 * s1.x + h1 * s1.y + h2 * s1.z + h3 * s1.w;
        }
      }
      pmu += __shfl_xor(pmu, 32);
      psc += __shfl_xor(psc, 32);
      if (kq == 0) part2mu[wave * 33 + m] = pmu;   // both halves hold both sums:
      else         part2sc[wave * 33 + m] = psc;   // split the stores across kq
    }

    // zero next delta buffer (640 words; last read of it was >=1 barrier ago)
    ((unsigned*)dbuf[nb])[tid] = 0u;
    if (tid < 128) ((unsigned*)dbuf[nb])[512 + tid] = 0u;

    // stage-write (latency hidden under phase A/B)
    if (tid < 128) *(float4*)&w1s[tid * 4] = w1stg;
    else if (tid < 384 && d < 63) *(float4*)&w3fs[nb][c_sel][j0] = w3stg;
    __syncthreads();

    // --- B2 (replicated): sum 8 wave partials, softplus, sample
    float msum = b3s[d], ssum = b3s[64 + d];
    #pragma unroll
    for (int w = 0; w < 8; ++w) {
      msum += part2mu[w * 33 + rA];
      ssum += part2sc[w * 33 + rA];
    }
    const float mu = msum;
    const float sc = softplus_f(ssum);
    const float z  = fmaf(sc, epsall[rA * 65 + d], mu);
    if (tid < 32) {
      zLb[rA * 65 + d]  = z;
      muLb[rA * 65 + d] = mu;
      scLb[rA * 65 + d] = sc;
    }

    // --- Phase C: rank-1 a1 update (guard-free fast path) + freeze into next delta
    const int kbw = Cd >> 4;
    if (jA >= Cd) {                 // fully in suffix: no per-element guards
      #pragma unroll
      for (int i = 0; i < 32; ++i) a1r[i] += z * w1s[jA + i];
    } else if (jA + 31 >= Cd) {     // boundary wave only
      #pragma unroll
      for (int i = 0; i < 32; ++i) {
        int j = jA + i;
        if (j >= Cd) a1r[i] += z * w1s[j];
      }
    }
    if (jA < Cnext && jA + 31 >= Cd) {
      #pragma unroll
      for (int i = 0; i < 32; ++i) {
        int j = jA + i;
        if (j >= Cd && j < Cnext) {
          dbuf[nb][rA][j - kbw * 16] = f2bfu(fmaxf(a1r[i], 0.f));
        }
      }
    }
    __syncthreads();
  }

  // --- final coalesced flush of z/mu/sc
  {
    const int r = tid >> 4, c = (tid & 15) * 4;
    float4 zv, mv, sv;
    zv.x = zLb[r * 65 + c + 0]; zv.y = zLb[r * 65 + c + 1];
    zv.z = zLb[r * 65 + c + 2]; zv.w = zLb[r * 65 + c + 3];
    mv.x = muLb[r * 65 + c + 0]; mv.y = muLb[r * 65 + c + 1];
    mv.z = muLb[r * 65 + c + 2]; mv.w = muLb[r * 65 + c + 3];
    sv.x = scLb[r * 65 + c + 0]; sv.y = scLb[r * 65 + c + 1];
    sv.z = scLb[r * 65 + c + 2]; sv.w = scLb[r * 65 + c + 3];
    *(float4*)&out[(g0 + r) * 64 + c]           = zv;
    *(float4*)&out[2097152 + (g0 + r) * 64 + c] = mv;
    *(float4*)&out[4194304 + (g0 + r) * 64 + c] = sv;
  }
}

extern "C" void kernel_launch(void* const* d_in, const int* in_sizes, int n_in,
                              void* d_out, int out_size, void* d_ws, size_t ws_size,
                              hipStream_t stream) {
  (void)in_sizes; (void)n_in; (void)out_size; (void)ws_size;
  const float* context = (const float*)d_in[0];
  const float* eps     = (const float*)d_in[1];
  const float* W1      = (const float*)d_in[2];
  const float* Wc      = (const float*)d_in[3];
  const float* b1      = (const float*)d_in[4];
  const float* W2      = (const float*)d_in[5];
  const float* b2      = (const float*)d_in[6];
  const float* W3      = (const float*)d_in[7];
  const float* b3      = (const float*)d_in[8];
  float* out = (float*)d_out;

  // ws: ctxp f32[1048576] | mw1s f32[32768] | b2s f32[512] | mw3f f32[65536] | mw2f u16[262144]
  float* ws   = (float*)d_ws;
  float* ctxp = ws;
  float* mw1s = ctxp + 1048576;
  float* b2s  = mw1s + 32768;
  float* mw3f = b2s + 512;
  u16*   mw2f = (u16*)(mw3f + 65536);

  prep_w<<<1410, 256, 0, stream>>>(W1, W2, b2, W3, mw1s, mw2f, mw3f, b2s);
  prep_ctx<<<128, 512, 0, stream>>>(context, Wc, b1, ctxp);
  made_main<<<1024, TPB, 0, stream>>>(eps, b3, ctxp, mw1s, mw3f, b2s, mw2f, out);
}